// Round 1
// baseline (136.798 us; speedup 1.0000x reference)
//
#include <hip/hip_runtime.h>
#include <hip/hip_bf16.h>
#include <math.h>

#define NPG    23
#define HID    48
#define HEADS  4
#define C1     192   // HEADS*HID
#define NFEAT  11
#define GG     1024  // B*T graphs
#define GRUH   64
#define FRAME  96
#define TT     16
#define BB     64

__device__ __forceinline__ float sigmoidf_(float x) {
    return 1.0f / (1.0f + __expf(-x));
}

// ---------------------------------------------------------------------------
// Kernel 1: per-graph fused GAT1(4 heads) -> ELU -> GAT2(1 head) -> ELU ->
//           mean/max pool -> frames (G x 96).  One block per graph.
// ---------------------------------------------------------------------------
__global__ __launch_bounds__(256) void gat_fused(
    const float* __restrict__ x,      // NTOT x 11
    const float* __restrict__ W1,     // 11 x 192
    const float* __restrict__ as1,    // 4 x 48
    const float* __restrict__ ad1,    // 4 x 48
    const float* __restrict__ b1,     // 192
    const float* __restrict__ W2,     // 192 x 48
    const float* __restrict__ as2,    // 48
    const float* __restrict__ ad2,    // 48
    const float* __restrict__ b2,     // 48
    float* __restrict__ frames)       // G x 96
{
    __shared__ float sh_x[NPG][NFEAT];
    __shared__ float sh_h[NPG][C1];        // GAT1 pre-attention features
    __shared__ float sh_h1[NPG][C1];       // GAT1 output (post ELU)
    __shared__ float sh_als[NPG][HEADS];
    __shared__ float sh_ald[NPG][HEADS];
    __shared__ float sh_alpha[NPG][NPG][HEADS];  // [src][dst][head]
    __shared__ float sh_g[NPG][HID];       // GAT2 pre-attention features
    __shared__ float sh_als2[NPG];
    __shared__ float sh_ald2[NPG];
    __shared__ float sh_alpha2[NPG][NPG];  // [src][dst]
    __shared__ float sh_h2[NPG][HID];      // GAT2 output (post ELU)

    const int g   = blockIdx.x;
    const int tid = threadIdx.x;
    const int base = g * NPG;

    // ---- load x tile ----
    for (int idx = tid; idx < NPG * NFEAT; idx += 256) {
        int n = idx / NFEAT, k = idx % NFEAT;
        sh_x[n][k] = x[(base + n) * NFEAT + k];
    }
    __syncthreads();

    // ---- h = x @ W1  (23 x 192) ----
    for (int idx = tid; idx < NPG * C1; idx += 256) {
        int n = idx / C1, c = idx % C1;
        float s = 0.f;
        #pragma unroll
        for (int k = 0; k < NFEAT; k++) s += sh_x[n][k] * W1[k * C1 + c];
        sh_h[n][c] = s;
    }
    __syncthreads();

    // ---- attention logits al_s, al_d per (node, head) ----
    for (int idx = tid; idx < NPG * HEADS; idx += 256) {
        int n = idx / HEADS, hh = idx % HEADS;
        float ss = 0.f, sd = 0.f;
        #pragma unroll
        for (int d = 0; d < HID; d++) {
            float hv = sh_h[n][hh * HID + d];
            ss += hv * as1[hh * HID + d];
            sd += hv * ad1[hh * HID + d];
        }
        sh_als[n][hh] = ss;
        sh_ald[n][hh] = sd;
    }
    __syncthreads();

    // ---- softmax over src per (dst, head) ----
    for (int idx = tid; idx < NPG * HEADS; idx += 256) {
        int j = idx / HEADS, hh = idx % HEADS;
        float ald = sh_ald[j][hh];
        float m = -1e30f;
        #pragma unroll
        for (int i = 0; i < NPG; i++) {
            float e = sh_als[i][hh] + ald;
            e = (e > 0.f) ? e : 0.2f * e;
            m = fmaxf(m, e);
        }
        float ssum = 0.f;
        #pragma unroll
        for (int i = 0; i < NPG; i++) {
            float e = sh_als[i][hh] + ald;
            e = (e > 0.f) ? e : 0.2f * e;
            float w = __expf(e - m);
            sh_alpha[i][j][hh] = w;
            ssum += w;
        }
        float inv = 1.0f / (ssum + 1e-16f);
        #pragma unroll
        for (int i = 0; i < NPG; i++) sh_alpha[i][j][hh] *= inv;
    }
    __syncthreads();

    // ---- aggregate + b1 + ELU -> sh_h1 ----
    for (int idx = tid; idx < NPG * C1; idx += 256) {
        int j = idx / C1, c = idx % C1;
        int hh = c / HID;
        float s = 0.f;
        #pragma unroll
        for (int i = 0; i < NPG; i++) s += sh_alpha[i][j][hh] * sh_h[i][c];
        float v = s + b1[c];
        sh_h1[j][c] = (v > 0.f) ? v : expm1f(v);
    }
    __syncthreads();

    // ---- g = h1 @ W2  (23 x 48) ----
    for (int idx = tid; idx < NPG * HID; idx += 256) {
        int n = idx / HID, c = idx % HID;
        float s = 0.f;
        for (int k = 0; k < C1; k++) s += sh_h1[n][k] * W2[k * HID + c];
        sh_g[n][c] = s;
    }
    __syncthreads();

    // ---- layer-2 attention logits ----
    for (int idx = tid; idx < NPG; idx += 256) {
        float ss = 0.f, sd = 0.f;
        #pragma unroll
        for (int d = 0; d < HID; d++) {
            float gv = sh_g[idx][d];
            ss += gv * as2[d];
            sd += gv * ad2[d];
        }
        sh_als2[idx] = ss;
        sh_ald2[idx] = sd;
    }
    __syncthreads();

    for (int idx = tid; idx < NPG; idx += 256) {
        int j = idx;
        float ald = sh_ald2[j];
        float m = -1e30f;
        #pragma unroll
        for (int i = 0; i < NPG; i++) {
            float e = sh_als2[i] + ald;
            e = (e > 0.f) ? e : 0.2f * e;
            m = fmaxf(m, e);
        }
        float ssum = 0.f;
        #pragma unroll
        for (int i = 0; i < NPG; i++) {
            float e = sh_als2[i] + ald;
            e = (e > 0.f) ? e : 0.2f * e;
            float w = __expf(e - m);
            sh_alpha2[i][j] = w;
            ssum += w;
        }
        float inv = 1.0f / (ssum + 1e-16f);
        #pragma unroll
        for (int i = 0; i < NPG; i++) sh_alpha2[i][j] *= inv;
    }
    __syncthreads();

    // ---- aggregate2 + b2 + ELU -> sh_h2 ----
    for (int idx = tid; idx < NPG * HID; idx += 256) {
        int j = idx / HID, d = idx % HID;
        float s = 0.f;
        #pragma unroll
        for (int i = 0; i < NPG; i++) s += sh_alpha2[i][j] * sh_g[i][d];
        float v = s + b2[d];
        sh_h2[j][d] = (v > 0.f) ? v : expm1f(v);
    }
    __syncthreads();

    // ---- mean/max pool -> frames ----
    for (int idx = tid; idx < HID; idx += 256) {
        float sm = 0.f, mx = -1e30f;
        #pragma unroll
        for (int j = 0; j < NPG; j++) {
            float v = sh_h2[j][idx];
            sm += v;
            mx = fmaxf(mx, v);
        }
        frames[g * FRAME + idx]       = sm * (1.0f / NPG);
        frames[g * FRAME + HID + idx] = mx;
    }
}

// ---------------------------------------------------------------------------
// Kernel 2: 2-layer GRU over T=16 + MLP head.  One block per sequence (B=64).
// 576 threads: [0,192) own Whh0 rows, [192,384) own Wih1 rows,
//              [384,576) own Whh1 rows — weights register-resident.
// ---------------------------------------------------------------------------
__global__ __launch_bounds__(576) void gru_head(
    const float* __restrict__ frames, // (B*T) x 96
    const float* __restrict__ Wih0,   // 192 x 96
    const float* __restrict__ Whh0,   // 192 x 64
    const float* __restrict__ bih0,
    const float* __restrict__ bhh0,
    const float* __restrict__ Wih1,   // 192 x 64
    const float* __restrict__ Whh1,   // 192 x 64
    const float* __restrict__ bih1,
    const float* __restrict__ bhh1,
    const float* __restrict__ Wh1,    // 64 x 32
    const float* __restrict__ bh1,    // 32
    const float* __restrict__ Wh2,    // 32 x 1
    const float* __restrict__ bh2,    // 1
    float* __restrict__ out)          // 64
{
    __shared__ float sh_f[TT * FRAME];     // frames for this sequence
    __shared__ float sh_gi0[TT][C1];       // precomputed input gates, layer 0
    __shared__ float sh_h0[GRUH];
    __shared__ float sh_h1[GRUH];
    __shared__ float sh_gh0[C1];
    __shared__ float sh_gh1[C1];
    __shared__ float sh_gi1[C1];
    __shared__ float sh_t1[32];

    const int b   = blockIdx.x;
    const int tid = threadIdx.x;

    for (int idx = tid; idx < TT * FRAME; idx += 576)
        sh_f[idx] = frames[b * TT * FRAME + idx];
    if (tid < GRUH) { sh_h0[tid] = 0.f; sh_h1[tid] = 0.f; }
    __syncthreads();

    // gi0 for all timesteps (no recurrent dependence)
    for (int idx = tid; idx < TT * C1; idx += 576) {
        int t = idx / C1, c = idx % C1;
        float s = bih0[c];
        #pragma unroll 8
        for (int k = 0; k < FRAME; k++) s += sh_f[t * FRAME + k] * Wih0[c * FRAME + k];
        sh_gi0[t][c] = s;
    }

    // register-resident recurrent weights (64 floats / thread)
    float w[64];
    const float* wp = (tid < 192) ? &Whh0[tid * 64]
                   : (tid < 384) ? &Wih1[(tid - 192) * 64]
                                 : &Whh1[(tid - 384) * 64];
    #pragma unroll
    for (int k = 0; k < 16; k++) {
        float4 v = reinterpret_cast<const float4*>(wp)[k];
        w[4 * k]     = v.x;
        w[4 * k + 1] = v.y;
        w[4 * k + 2] = v.z;
        w[4 * k + 3] = v.w;
    }
    float bias = (tid < 192) ? bhh0[tid]
               : (tid < 384) ? bih1[tid - 192]
                             : bhh1[tid - 384];
    __syncthreads();

    for (int t = 0; t < TT; t++) {
        // phase 1: gh0 (uses h0_{t-1}) and gh1 (uses h1_{t-1})
        if (tid < 192) {
            float s = bias;
            #pragma unroll
            for (int k = 0; k < 64; k++) s += w[k] * sh_h0[k];
            sh_gh0[tid] = s;
        } else if (tid >= 384) {
            float s = bias;
            #pragma unroll
            for (int k = 0; k < 64; k++) s += w[k] * sh_h1[k];
            sh_gh1[tid - 384] = s;
        }
        __syncthreads();

        // phase 2: layer-0 hidden update
        if (tid < GRUH) {
            float r = sigmoidf_(sh_gi0[t][tid]       + sh_gh0[tid]);
            float z = sigmoidf_(sh_gi0[t][64 + tid]  + sh_gh0[64 + tid]);
            float n = tanhf(sh_gi0[t][128 + tid] + r * sh_gh0[128 + tid]);
            sh_h0[tid] = (1.f - z) * n + z * sh_h0[tid];
        }
        __syncthreads();

        // phase 3: gi1 from the new h0
        if (tid >= 192 && tid < 384) {
            float s = bias;
            #pragma unroll
            for (int k = 0; k < 64; k++) s += w[k] * sh_h0[k];
            sh_gi1[tid - 192] = s;
        }
        __syncthreads();

        // phase 4: layer-1 hidden update
        if (tid < GRUH) {
            float r = sigmoidf_(sh_gi1[tid]      + sh_gh1[tid]);
            float z = sigmoidf_(sh_gi1[64 + tid] + sh_gh1[64 + tid]);
            float n = tanhf(sh_gi1[128 + tid] + r * sh_gh1[128 + tid]);
            sh_h1[tid] = (1.f - z) * n + z * sh_h1[tid];
        }
        __syncthreads();
    }

    // ---- head: relu(last @ Wh1 + bh1) @ Wh2 + bh2 ----
    if (tid < 32) {
        float s = bh1[tid];
        #pragma unroll
        for (int k = 0; k < GRUH; k++) s += sh_h1[k] * Wh1[k * 32 + tid];
        sh_t1[tid] = fmaxf(s, 0.f);
    }
    __syncthreads();
    if (tid == 0) {
        float s = bh2[0];
        #pragma unroll
        for (int k = 0; k < 32; k++) s += sh_t1[k] * Wh2[k];
        out[b] = s;
    }
}

extern "C" void kernel_launch(void* const* d_in, const int* in_sizes, int n_in,
                              void* d_out, int out_size, void* d_ws, size_t ws_size,
                              hipStream_t stream) {
    const float* x    = (const float*)d_in[0];
    // d_in[1] = edge_index, d_in[2] = batch : structure is fixed/dense -> unused
    const float* W1   = (const float*)d_in[3];
    const float* as1  = (const float*)d_in[4];
    const float* ad1  = (const float*)d_in[5];
    const float* b1   = (const float*)d_in[6];
    const float* W2   = (const float*)d_in[7];
    const float* as2  = (const float*)d_in[8];
    const float* ad2  = (const float*)d_in[9];
    const float* b2   = (const float*)d_in[10];
    const float* Wih0 = (const float*)d_in[11];
    const float* Whh0 = (const float*)d_in[12];
    const float* bih0 = (const float*)d_in[13];
    const float* bhh0 = (const float*)d_in[14];
    const float* Wih1 = (const float*)d_in[15];
    const float* Whh1 = (const float*)d_in[16];
    const float* bih1 = (const float*)d_in[17];
    const float* bhh1 = (const float*)d_in[18];
    const float* Wh1  = (const float*)d_in[19];
    const float* bh1  = (const float*)d_in[20];
    const float* Wh2  = (const float*)d_in[21];
    const float* bh2  = (const float*)d_in[22];

    float* out    = (float*)d_out;
    float* frames = (float*)d_ws;   // G x 96 fp32 = 393 KB

    hipLaunchKernelGGL(gat_fused, dim3(GG), dim3(256), 0, stream,
                       x, W1, as1, ad1, b1, W2, as2, ad2, b2, frames);
    hipLaunchKernelGGL(gru_head, dim3(BB), dim3(576), 0, stream,
                       frames, Wih0, Whh0, bih0, bhh0,
                       Wih1, Whh1, bih1, bhh1, Wh1, bh1, Wh2, bh2, out);
}

// Round 2
// 93.802 us; speedup vs baseline: 1.4584x; 1.4584x over previous
//
#include <hip/hip_runtime.h>
#include <hip/hip_bf16.h>
#include <math.h>

#define NPG    23
#define HID    48
#define HEADS  4
#define C1     192   // HEADS*HID
#define NFEAT  11
#define GG     1024  // B*T graphs
#define GRUH   64
#define FRAME  96
#define TT     16
#define BB     64

// LDS layout (floats), total 9456 floats = 37824 B -> 4 blocks/CU
#define OFF_X    0      // 253 (x tile; reused as als2/ald2 later)
#define OFF_ALS  256    // 92  [hh*23+n]
#define OFF_ALD  348    // 92
#define OFF_H    440    // 23*196 = 4508 (reused as g + h2 later)
#define OFF_H1   4948   // 23*196 = 4508
#define LDS_FLOATS 9456
#define HSTR 196        // padded row stride for h/h1 (bank spread, float4 aligned)
#define GSTR 52         // padded row stride for g

// ---------------------------------------------------------------------------
// Kernel 1: per-graph fused GAT1(4 heads) -> ELU -> GAT2 -> ELU -> pool.
// One block (256 thr) per graph; 1024 blocks = exactly 4 blocks/CU.
// Softmax alphas live in registers (fused with aggregation); logit dot
// products folded into the GEMM phases via LDS f32 atomics.
// ---------------------------------------------------------------------------
__global__ __launch_bounds__(256, 4) void gat_fused(
    const float* __restrict__ x,      // NTOT x 11
    const float* __restrict__ W1,     // 11 x 192
    const float* __restrict__ as1,    // 4 x 48 (flat 192, matches c index)
    const float* __restrict__ ad1,    // 4 x 48
    const float* __restrict__ b1,     // 192
    const float* __restrict__ W2,     // 192 x 48
    const float* __restrict__ as2,    // 48
    const float* __restrict__ ad2,    // 48
    const float* __restrict__ b2,     // 48
    float* __restrict__ frames)       // G x 96
{
    __shared__ float S[LDS_FLOATS];
    float* s_x    = S + OFF_X;
    float* s_als  = S + OFF_ALS;
    float* s_ald  = S + OFF_ALD;
    float* s_h    = S + OFF_H;
    float* s_h1   = S + OFF_H1;
    float* s_g    = S + OFF_H;           // overlays h (dead after aggregate1)
    float* s_h2   = S + OFF_H + 1196;    // after g (23*52=1196)
    float* s_als2 = S + OFF_X;           // overlays x (dead after phase B)
    float* s_ald2 = S + OFF_X + 23;

    const int g   = blockIdx.x;
    const int tid = threadIdx.x;

    // ---- load x tile, zero als/ald accumulators ----
    for (int i = tid; i < NPG * NFEAT; i += 256) s_x[i] = x[g * NPG * NFEAT + i];
    for (int i = tid; i < 184; i += 256) s_als[i] = 0.f;  // covers als+ald (contiguous)
    __syncthreads();

    // ---- B: h = x@W1 (float4 over c) + logit partials via LDS atomics ----
    for (int task = tid; task < NPG * 48; task += 256) {
        int n = task / 48, c4 = task % 48;
        float xr[NFEAT];
        #pragma unroll
        for (int k = 0; k < NFEAT; k++) xr[k] = s_x[n * NFEAT + k];
        float4 acc = {0.f, 0.f, 0.f, 0.f};
        #pragma unroll
        for (int k = 0; k < NFEAT; k++) {
            float4 w = *(const float4*)(W1 + k * C1 + 4 * c4);
            acc.x += xr[k] * w.x; acc.y += xr[k] * w.y;
            acc.z += xr[k] * w.z; acc.w += xr[k] * w.w;
        }
        *(float4*)(s_h + n * HSTR + 4 * c4) = acc;
        float4 a_s = *(const float4*)(as1 + 4 * c4);
        float4 a_d = *(const float4*)(ad1 + 4 * c4);
        int hh = c4 / 12;
        atomicAdd(&s_als[hh * NPG + n],
                  acc.x * a_s.x + acc.y * a_s.y + acc.z * a_s.z + acc.w * a_s.w);
        atomicAdd(&s_ald[hh * NPG + n],
                  acc.x * a_d.x + acc.y * a_d.y + acc.z * a_d.z + acc.w * a_d.w);
    }
    __syncthreads();

    // ---- E': fused softmax1 (alpha in regs) + aggregate + b1 + ELU -> h1 ----
    if (tid < 184) {
        int j = tid >> 3, sub = tid & 7;
        int hh = sub >> 1, half = sub & 1;
        float ald_j = s_ald[hh * NPG + j];
        float a[NPG];
        float m = -1e30f;
        #pragma unroll
        for (int i = 0; i < NPG; i++) {
            float e = s_als[hh * NPG + i] + ald_j;
            e = (e > 0.f) ? e : 0.2f * e;
            a[i] = e;
            m = fmaxf(m, e);
        }
        float ssum = 0.f;
        #pragma unroll
        for (int i = 0; i < NPG; i++) {
            float w = __expf(a[i] - m);
            a[i] = w;
            ssum += w;
        }
        float inv = 1.f / (ssum + 1e-16f);
        int cb = hh * 48 + half * 24;
        #pragma unroll
        for (int c4 = 0; c4 < 6; c4++) {
            float4 acc = {0.f, 0.f, 0.f, 0.f};
            #pragma unroll
            for (int i = 0; i < NPG; i++) {
                float4 hv = *(const float4*)(s_h + i * HSTR + cb + 4 * c4);
                acc.x += a[i] * hv.x; acc.y += a[i] * hv.y;
                acc.z += a[i] * hv.z; acc.w += a[i] * hv.w;
            }
            float4 bb = *(const float4*)(b1 + cb + 4 * c4);
            acc.x = acc.x * inv + bb.x; acc.y = acc.y * inv + bb.y;
            acc.z = acc.z * inv + bb.z; acc.w = acc.w * inv + bb.w;
            acc.x = (acc.x > 0.f) ? acc.x : __expf(acc.x) - 1.f;
            acc.y = (acc.y > 0.f) ? acc.y : __expf(acc.y) - 1.f;
            acc.z = (acc.z > 0.f) ? acc.z : __expf(acc.z) - 1.f;
            acc.w = (acc.w > 0.f) ? acc.w : __expf(acc.w) - 1.f;
            *(float4*)(s_h1 + j * HSTR + cb + 4 * c4) = acc;
        }
    } else if (tid < 184 + 46) {
        s_als2[tid - 184] = 0.f;  // zero als2+ald2 (x region, contiguous 46)
    }
    __syncthreads();

    // ---- F: g = h1 @ W2 + logit2 partials via LDS atomics ----
    for (int task = tid; task < NPG * 12; task += 256) {
        int n = task / 12, c4 = task % 12;
        float4 acc = {0.f, 0.f, 0.f, 0.f};
        const float4* w2p = (const float4*)W2 + c4;  // row stride = 12 float4
        #pragma unroll 4
        for (int k4 = 0; k4 < 48; k4++) {
            float4 hv = *(const float4*)(s_h1 + n * HSTR + 4 * k4);
            float4 r0 = w2p[(4 * k4 + 0) * 12];
            float4 r1 = w2p[(4 * k4 + 1) * 12];
            float4 r2 = w2p[(4 * k4 + 2) * 12];
            float4 r3 = w2p[(4 * k4 + 3) * 12];
            acc.x += hv.x * r0.x + hv.y * r1.x + hv.z * r2.x + hv.w * r3.x;
            acc.y += hv.x * r0.y + hv.y * r1.y + hv.z * r2.y + hv.w * r3.y;
            acc.z += hv.x * r0.z + hv.y * r1.z + hv.z * r2.z + hv.w * r3.z;
            acc.w += hv.x * r0.w + hv.y * r1.w + hv.z * r2.w + hv.w * r3.w;
        }
        float4 a_s = *(const float4*)(as2 + 4 * c4);
        float4 a_d = *(const float4*)(ad2 + 4 * c4);
        atomicAdd(&s_als2[n],
                  acc.x * a_s.x + acc.y * a_s.y + acc.z * a_s.z + acc.w * a_s.w);
        atomicAdd(&s_ald2[n],
                  acc.x * a_d.x + acc.y * a_d.y + acc.z * a_d.z + acc.w * a_d.w);
        *(float4*)(s_g + n * GSTR + 4 * c4) = acc;
    }
    __syncthreads();

    // ---- H': fused softmax2 (regs) + aggregate2 + b2 + ELU -> h2 ----
    if (tid < 92) {
        int j = tid >> 2, q = tid & 3;
        float ald_j = s_ald2[j];
        float a[NPG];
        float m = -1e30f;
        #pragma unroll
        for (int i = 0; i < NPG; i++) {
            float e = s_als2[i] + ald_j;
            e = (e > 0.f) ? e : 0.2f * e;
            a[i] = e;
            m = fmaxf(m, e);
        }
        float ssum = 0.f;
        #pragma unroll
        for (int i = 0; i < NPG; i++) {
            float w = __expf(a[i] - m);
            a[i] = w;
            ssum += w;
        }
        float inv = 1.f / (ssum + 1e-16f);
        #pragma unroll
        for (int c4 = 0; c4 < 3; c4++) {
            int cb = q * 12 + 4 * c4;
            float4 acc = {0.f, 0.f, 0.f, 0.f};
            #pragma unroll
            for (int i = 0; i < NPG; i++) {
                float4 gv = *(const float4*)(s_g + i * GSTR + cb);
                acc.x += a[i] * gv.x; acc.y += a[i] * gv.y;
                acc.z += a[i] * gv.z; acc.w += a[i] * gv.w;
            }
            float4 bb = *(const float4*)(b2 + cb);
            acc.x = acc.x * inv + bb.x; acc.y = acc.y * inv + bb.y;
            acc.z = acc.z * inv + bb.z; acc.w = acc.w * inv + bb.w;
            acc.x = (acc.x > 0.f) ? acc.x : __expf(acc.x) - 1.f;
            acc.y = (acc.y > 0.f) ? acc.y : __expf(acc.y) - 1.f;
            acc.z = (acc.z > 0.f) ? acc.z : __expf(acc.z) - 1.f;
            acc.w = (acc.w > 0.f) ? acc.w : __expf(acc.w) - 1.f;
            *(float4*)(s_h2 + j * 48 + cb) = acc;
        }
    }
    __syncthreads();

    // ---- pool -> frames ----
    if (tid < 48) {
        float sm = 0.f, mx = -1e30f;
        #pragma unroll
        for (int jj = 0; jj < NPG; jj++) {
            float v = s_h2[jj * 48 + tid];
            sm += v;
            mx = fmaxf(mx, v);
        }
        frames[g * FRAME + tid]       = sm * (1.0f / NPG);
        frames[g * FRAME + 48 + tid]  = mx;
    }
}

// ---------------------------------------------------------------------------
// Kernel 2: 2-layer GRU (T=16) + MLP head. One block (192 thr / 3 waves) per
// sequence. Thread r holds row r of Whh0, Wih1, Whh1 in 192 VGPRs; the
// recurrent dot64s are 16 ds_read_b128 broadcasts + 64 FMA each.
// ---------------------------------------------------------------------------
__global__ __launch_bounds__(192) void gru_head(
    const float* __restrict__ frames, // (B*T) x 96
    const float* __restrict__ Wih0,   // 192 x 96
    const float* __restrict__ Whh0,   // 192 x 64
    const float* __restrict__ bih0,
    const float* __restrict__ bhh0,
    const float* __restrict__ Wih1,   // 192 x 64
    const float* __restrict__ Whh1,   // 192 x 64
    const float* __restrict__ bih1,
    const float* __restrict__ bhh1,
    const float* __restrict__ Wh1,    // 64 x 32
    const float* __restrict__ bh1,    // 32
    const float* __restrict__ Wh2,    // 32 x 1
    const float* __restrict__ bh2,    // 1
    float* __restrict__ out)          // 64
{
    __shared__ float s_f[TT * FRAME];    // 1536
    __shared__ float s_gi0[TT * C1];     // 3072
    __shared__ float s_h0[GRUH], s_h1s[GRUH];
    __shared__ float s_gh0[C1], s_gh1[C1], s_gi1[C1];
    __shared__ float s_t1[32];

    const int b = blockIdx.x, tid = threadIdx.x;

    for (int i = tid; i < TT * FRAME; i += 192) s_f[i] = frames[b * TT * FRAME + i];
    if (tid < GRUH) { s_h0[tid] = 0.f; s_h1s[tid] = 0.f; }
    __syncthreads();

    // ---- gi0 for all timesteps (k-outer: each thread loads its Wih0 row once) ----
    {
        float acc[TT];
        float b0 = bih0[tid];
        #pragma unroll
        for (int t = 0; t < TT; t++) acc[t] = b0;
        const float4* wr = (const float4*)(Wih0 + tid * FRAME);
        const float4* f4 = (const float4*)s_f;
        #pragma unroll 4
        for (int k4 = 0; k4 < FRAME / 4; k4++) {
            float4 w = wr[k4];
            #pragma unroll
            for (int t = 0; t < TT; t++) {
                float4 f = f4[t * (FRAME / 4) + k4];
                acc[t] += w.x * f.x + w.y * f.y + w.z * f.z + w.w * f.w;
            }
        }
        #pragma unroll
        for (int t = 0; t < TT; t++) s_gi0[t * C1 + tid] = acc[t];
    }

    // ---- register-resident recurrent weight rows ----
    float w0[64], w1[64], w2[64];
    {
        const float4* p0 = (const float4*)(Whh0 + tid * 64);
        const float4* p1 = (const float4*)(Wih1 + tid * 64);
        const float4* p2 = (const float4*)(Whh1 + tid * 64);
        #pragma unroll
        for (int k4 = 0; k4 < 16; k4++) {
            float4 v0 = p0[k4];
            w0[4*k4] = v0.x; w0[4*k4+1] = v0.y; w0[4*k4+2] = v0.z; w0[4*k4+3] = v0.w;
            float4 v1 = p1[k4];
            w1[4*k4] = v1.x; w1[4*k4+1] = v1.y; w1[4*k4+2] = v1.z; w1[4*k4+3] = v1.w;
            float4 v2 = p2[k4];
            w2[4*k4] = v2.x; w2[4*k4+1] = v2.y; w2[4*k4+2] = v2.z; w2[4*k4+3] = v2.w;
        }
    }
    const float bh0r = bhh0[tid], bi1r = bih1[tid], bh1r = bhh1[tid];
    __syncthreads();   // covers gi0 writes too

    const float4* h0v4 = (const float4*)s_h0;
    const float4* h1v4 = (const float4*)s_h1s;

    for (int t = 0; t < TT; t++) {
        // P1: gh0 (from h0_{t-1}) and gh1 (from h1_{t-1}), all 192 threads
        {
            float s0 = bh0r, s1 = bh1r;
            #pragma unroll
            for (int k4 = 0; k4 < 16; k4++) {
                float4 a = h0v4[k4];
                float4 c = h1v4[k4];
                s0 += w0[4*k4]*a.x + w0[4*k4+1]*a.y + w0[4*k4+2]*a.z + w0[4*k4+3]*a.w;
                s1 += w2[4*k4]*c.x + w2[4*k4+1]*c.y + w2[4*k4+2]*c.z + w2[4*k4+3]*c.w;
            }
            s_gh0[tid] = s0;
            s_gh1[tid] = s1;
        }
        __syncthreads();
        // P2: layer-0 hidden update
        if (tid < GRUH) {
            float ir = s_gi0[t*C1 + tid], iz = s_gi0[t*C1 + 64 + tid], in_ = s_gi0[t*C1 + 128 + tid];
            float hr = s_gh0[tid], hz = s_gh0[64 + tid], hn = s_gh0[128 + tid];
            float r = 1.f / (1.f + __expf(-(ir + hr)));
            float z = 1.f / (1.f + __expf(-(iz + hz)));
            float nx = in_ + r * hn;
            float e2 = __expf(2.f * nx);
            float n = (e2 - 1.f) / (e2 + 1.f);
            s_h0[tid] = (1.f - z) * n + z * s_h0[tid];
        }
        __syncthreads();
        // P3: gi1 from new h0
        {
            float s = bi1r;
            #pragma unroll
            for (int k4 = 0; k4 < 16; k4++) {
                float4 a = h0v4[k4];
                s += w1[4*k4]*a.x + w1[4*k4+1]*a.y + w1[4*k4+2]*a.z + w1[4*k4+3]*a.w;
            }
            s_gi1[tid] = s;
        }
        __syncthreads();
        // P4: layer-1 hidden update
        if (tid < GRUH) {
            float ir = s_gi1[tid], iz = s_gi1[64 + tid], in_ = s_gi1[128 + tid];
            float hr = s_gh1[tid], hz = s_gh1[64 + tid], hn = s_gh1[128 + tid];
            float r = 1.f / (1.f + __expf(-(ir + hr)));
            float z = 1.f / (1.f + __expf(-(iz + hz)));
            float nx = in_ + r * hn;
            float e2 = __expf(2.f * nx);
            float n = (e2 - 1.f) / (e2 + 1.f);
            s_h1s[tid] = (1.f - z) * n + z * s_h1s[tid];
        }
        __syncthreads();
    }

    // ---- head: relu(last @ Wh1 + bh1) @ Wh2 + bh2 ----
    if (tid < 32) {
        float s = bh1[tid];
        #pragma unroll
        for (int k = 0; k < GRUH; k++) s += s_h1s[k] * Wh1[k * 32 + tid];
        s_t1[tid] = fmaxf(s, 0.f);
    }
    __syncthreads();
    if (tid == 0) {
        float s = bh2[0];
        #pragma unroll
        for (int k = 0; k < 32; k++) s += s_t1[k] * Wh2[k];
        out[b] = s;
    }
}

extern "C" void kernel_launch(void* const* d_in, const int* in_sizes, int n_in,
                              void* d_out, int out_size, void* d_ws, size_t ws_size,
                              hipStream_t stream) {
    const float* x    = (const float*)d_in[0];
    // d_in[1] = edge_index, d_in[2] = batch : fixed dense structure -> unused
    const float* W1   = (const float*)d_in[3];
    const float* as1  = (const float*)d_in[4];
    const float* ad1  = (const float*)d_in[5];
    const float* b1   = (const float*)d_in[6];
    const float* W2   = (const float*)d_in[7];
    const float* as2  = (const float*)d_in[8];
    const float* ad2  = (const float*)d_in[9];
    const float* b2   = (const float*)d_in[10];
    const float* Wih0 = (const float*)d_in[11];
    const float* Whh0 = (const float*)d_in[12];
    const float* bih0 = (const float*)d_in[13];
    const float* bhh0 = (const float*)d_in[14];
    const float* Wih1 = (const float*)d_in[15];
    const float* Whh1 = (const float*)d_in[16];
    const float* bih1 = (const float*)d_in[17];
    const float* bhh1 = (const float*)d_in[18];
    const float* Wh1  = (const float*)d_in[19];
    const float* bh1  = (const float*)d_in[20];
    const float* Wh2  = (const float*)d_in[21];
    const float* bh2  = (const float*)d_in[22];

    float* out    = (float*)d_out;
    float* frames = (float*)d_ws;   // G x 96 fp32 = 393 KB

    hipLaunchKernelGGL(gat_fused, dim3(GG), dim3(256), 0, stream,
                       x, W1, as1, ad1, b1, W2, as2, ad2, b2, frames);
    hipLaunchKernelGGL(gru_head, dim3(BB), dim3(192), 0, stream,
                       frames, Wih0, Whh0, bih0, bhh0,
                       Wih1, Whh1, bih1, bhh1, Wh1, bh1, Wh2, bh2, out);
}